// Round 1
// baseline (248.698 us; speedup 1.0000x reference)
//
#include <hip/hip_runtime.h>
#include <math.h>

#define BB 32
#define PP 2048
#define CC 512
#define TT 128            // PP/16
#define NROWS (BB*PP)     // 65536

// Kernel A: mean over C (contiguous 512 floats) for each of 65536 rows.
// One wave (64 lanes) per row; 4 waves per 256-thread block.
__global__ __launch_bounds__(256) void row_mean_kernel(
        const float* __restrict__ x, float* __restrict__ mean) {
    int wave = threadIdx.x >> 6;
    int lane = threadIdx.x & 63;
    int row  = blockIdx.x * 4 + wave;
    const float4* xr = (const float4*)(x + (size_t)row * CC);  // 128 float4/row
    float4 a = xr[lane];
    float4 b = xr[lane + 64];
    float s = (a.x + a.y) + (a.z + a.w) + (b.x + b.y) + (b.z + b.w);
    #pragma unroll
    for (int off = 32; off > 0; off >>= 1)
        s += __shfl_down(s, off, 64);
    if (lane == 0) mean[row] = s * (1.0f / 512.0f);
}

// Kernel B: 27-point stencil on mean[b][t][h][w] + sigmoid.
// Combined weight at offset (i-1,j-1,k-1):
//   w3[i][j][k] + (i<2&&j<2&&k<2 ? w2[i][j][k] : 0) + (center ? w1 : 0)
__global__ __launch_bounds__(256) void gate_kernel(
        const float* __restrict__ mean,
        const float* __restrict__ w1, const float* __restrict__ w2,
        const float* __restrict__ w3, float* __restrict__ gate) {
    int r = blockIdx.x * blockDim.x + threadIdx.x;
    if (r >= NROWS) return;
    int b = r >> 11;          // /2048
    int p = r & 2047;
    int t = p >> 4;
    int h = (p >> 2) & 3;
    int w = p & 3;
    const float* mb = mean + ((size_t)b << 11);
    float g = 0.0f;
    #pragma unroll
    for (int i = 0; i < 3; ++i) {
        int tt = t + i - 1;
        if (tt < 0 || tt >= TT) continue;
        #pragma unroll
        for (int j = 0; j < 3; ++j) {
            int hh = h + j - 1;
            if (hh < 0 || hh >= 4) continue;
            #pragma unroll
            for (int k = 0; k < 3; ++k) {
                int ww = w + k - 1;
                if (ww < 0 || ww >= 4) continue;
                float wt = w3[i * 9 + j * 3 + k];
                if (i < 2 && j < 2 && k < 2) wt += w2[i * 4 + j * 2 + k];
                if (i == 1 && j == 1 && k == 1) wt += w1[0];
                g += wt * mb[tt * 16 + hh * 4 + ww];
            }
        }
    }
    gate[r] = 1.0f / (1.0f + __expf(-g));
}

// Kernel C: out[b,p,c] = x[b,p,c] * gate[b*P+p], float4-vectorized.
__global__ __launch_bounds__(256) void scale_kernel(
        const float* __restrict__ x, const float* __restrict__ gate,
        float* __restrict__ out) {
    size_t q = (size_t)blockIdx.x * blockDim.x + threadIdx.x;  // float4 index
    int r = (int)(q >> 7);            // 128 float4 per row
    float s = gate[r];
    float4 v = ((const float4*)x)[q];
    v.x *= s; v.y *= s; v.z *= s; v.w *= s;
    ((float4*)out)[q] = v;
}

extern "C" void kernel_launch(void* const* d_in, const int* in_sizes, int n_in,
                              void* d_out, int out_size, void* d_ws, size_t ws_size,
                              hipStream_t stream) {
    const float* x  = (const float*)d_in[0];
    const float* w1 = (const float*)d_in[1];
    const float* w2 = (const float*)d_in[2];
    const float* w3 = (const float*)d_in[3];
    float* out  = (float*)d_out;
    float* mean = (float*)d_ws;            // 65536 floats
    float* gate = mean + NROWS;            // 65536 floats

    // A: 65536 rows / 4 waves per block
    row_mean_kernel<<<NROWS / 4, 256, 0, stream>>>(x, mean);
    // B: 65536 gates
    gate_kernel<<<NROWS / 256, 256, 0, stream>>>(mean, w1, w2, w3, gate);
    // C: 65536*128 float4 elements
    scale_kernel<<<(NROWS * (CC / 4)) / 256, 256, 0, stream>>>(x, gate, out);
}